// Round 12
// baseline (203737.024 us; speedup 1.0000x reference)
//
#include <hip/hip_runtime.h>

#define S_LEN 65536
#define HDIM 128

typedef _Float16 half2_t __attribute__((ext_vector_type(2)));
typedef _Float16 half4_t __attribute__((ext_vector_type(4)));
typedef _Float16 half8_t __attribute__((ext_vector_type(8)));
typedef float f32x4 __attribute__((ext_vector_type(4)));

__device__ __forceinline__ float sigm(float x) {
    return 1.0f / (1.0f + __expf(-x));
}
__device__ __forceinline__ float tanh_fast(float x) {
    return 2.0f / (1.0f + __expf(-2.0f * x)) - 1.0f;
}
__device__ __forceinline__ float dot2(half2_t a, half2_t b, float c) {
#if __has_builtin(__builtin_amdgcn_fdot2)
    return __builtin_amdgcn_fdot2(a, b, c, false);
#else
    return fmaf((float)a.x, (float)b.x, fmaf((float)a.y, (float)b.y, c));
#endif
}

// lgkmcnt-only barrier (validated correct + fast in R9).
__device__ __forceinline__ void block_sync_lds() {
    asm volatile("s_waitcnt lgkmcnt(0)" ::: "memory");
    __builtin_amdgcn_s_barrier();
}

// ================= Kernel 1: single-barrier MFMA recurrence ================
// R11 post-mortem: 1630 cyc/step = 620 MFMA pipe (hard floor for f16
// 16x16x32 matvec) + ~1000 latency skeleton (B-frag read, gates LDS
// round-trip over barrier 1, activation chain, barrier 2). This round:
//  - R10 tile mapping: wave w owns ALL 4 gates of rows [16w,16w+16) ->
//    gates stay in the producing wave's accs; phase B in-register on the
//    m==0 lanes (R11 proved phase-B issue cost is off the critical path).
//  - xg+bias folded into MFMA via K-extension (chunk 4: A=[W_ih|b|0...],
//    B=[x0,x1,1,0...]) -> zero per-row phase-B constants (R10's spill).
//  - A-frags pinned to AGPRs ("+a"): 80 regs off the VGPR budget.
//  - ONE barrier per step; h ping-pongs through 512 B of LDS.
__global__ __launch_bounds__(512)
__attribute__((amdgpu_waves_per_eu(2, 2)))
void lstm_seq_mfma(const float* __restrict__ x,
                   const float* __restrict__ h0,
                   const float* __restrict__ c0,
                   const float* __restrict__ W_ih,
                   const float* __restrict__ W_hh,
                   const float* __restrict__ b_ih,
                   const float* __restrict__ b_hh,
                   _Float16* __restrict__ h_hist)
{
    __shared__ __align__(16) _Float16 hbuf[2][HDIM];   // ping-pong h_t

    const int tid  = threadIdx.x;       // 0..511, 8 waves
    const int lane = tid & 63;
    const int w    = tid >> 6;          // wave id: rows [16w, 16w+16), all gates
    const int m    = lane & 15;         // A row within tile / D col
    const int quad = lane >> 4;         // 0..3

    // ---- A fragments: tile g = gate g, rows g*128 + 16w + m ----
    // chunks 0..3 = W_hh k in [32kc, 32kc+32); chunk 4 = [W_ih | bias | 0].
#define LOAD_AF(g, kc) \
    half8_t af_##g##_##kc; { \
        const float* s_ = W_hh + (size_t)((g) * 128 + 16 * w + m) * HDIM \
                               + 32 * (kc) + 8 * quad; \
        af_##g##_##kc = (half8_t){ \
            (_Float16)s_[0], (_Float16)s_[1], (_Float16)s_[2], (_Float16)s_[3], \
            (_Float16)s_[4], (_Float16)s_[5], (_Float16)s_[6], (_Float16)s_[7] }; \
        asm volatile("" : "+a"(af_##g##_##kc)); }
    LOAD_AF(0, 0) LOAD_AF(0, 1) LOAD_AF(0, 2) LOAD_AF(0, 3)
    LOAD_AF(1, 0) LOAD_AF(1, 1) LOAD_AF(1, 2) LOAD_AF(1, 3)
    LOAD_AF(2, 0) LOAD_AF(2, 1) LOAD_AF(2, 2) LOAD_AF(2, 3)
    LOAD_AF(3, 0) LOAD_AF(3, 1) LOAD_AF(3, 2) LOAD_AF(3, 3)
#undef LOAD_AF
#define LOAD_AF4(g) \
    half8_t af_##g##_4 = (half8_t){0,0,0,0,0,0,0,0}; \
    if (quad == 0) { \
        const int row_ = (g) * 128 + 16 * w + m; \
        af_##g##_4[0] = (_Float16)W_ih[2 * row_]; \
        af_##g##_4[1] = (_Float16)W_ih[2 * row_ + 1]; \
        af_##g##_4[2] = (_Float16)(b_ih[row_] + b_hh[row_]); \
    } \
    asm volatile("" : "+a"(af_##g##_4));
    LOAD_AF4(0) LOAD_AF4(1) LOAD_AF4(2) LOAD_AF4(3)
#undef LOAD_AF4

    // ---- c state: rows base..base+3 on m==0 lanes ----
    const int base = 16 * w + 4 * quad;
    f32x4 c = {0.f, 0.f, 0.f, 0.f};
    if (m == 0) c = *(const f32x4*)(c0 + base);   // base*4B is 16B-aligned

    if (tid < HDIM) hbuf[0][tid] = (_Float16)h0[tid];
    __syncthreads();   // once, pre-loop

    const float2* xp = (const float2*)x;
    float2 xcur = xp[0];   // wave-uniform stream

    half8_t bf0 = (half8_t){0,0,0,0,0,0,0,0};
    half8_t bf1 = bf0, bf2 = bf0, bf3 = bf0, bf4 = bf0;

    #pragma unroll 1
    for (int t = 0; t < S_LEN; ++t) {
        const int p  = t & 1;
        const int tn = (t + 1 < S_LEN) ? (t + 1) : (S_LEN - 1);
        float2 xnext = xp[tn];   // prefetch

        // ---- B fragments: col 0 = [h; x; 1], lanes {0,16,32,48} ----
        if (m == 0) {
            const half8_t* hb = (const half8_t*)hbuf[p];
            bf0 = hb[quad];        // k =       8q+j
            bf1 = hb[4 + quad];    // k =  32 + 8q+j
            bf2 = hb[8 + quad];    // k =  64 + 8q+j
            bf3 = hb[12 + quad];   // k =  96 + 8q+j
        }
        if (lane == 0) {           // k = 128..135: (x0, x1, 1, 0...)
            bf4[0] = (_Float16)xcur.x;
            bf4[1] = (_Float16)xcur.y;
            bf4[2] = (_Float16)1.0f;
        }

        f32x4 acc0 = {0.f, 0.f, 0.f, 0.f};
        f32x4 acc1 = {0.f, 0.f, 0.f, 0.f};
        f32x4 acc2 = {0.f, 0.f, 0.f, 0.f};
        f32x4 acc3 = {0.f, 0.f, 0.f, 0.f};
#define MFMA_TILE(g) \
        acc##g = __builtin_amdgcn_mfma_f32_16x16x32_f16(af_##g##_0, bf0, acc##g, 0, 0, 0); \
        acc##g = __builtin_amdgcn_mfma_f32_16x16x32_f16(af_##g##_1, bf1, acc##g, 0, 0, 0); \
        acc##g = __builtin_amdgcn_mfma_f32_16x16x32_f16(af_##g##_2, bf2, acc##g, 0, 0, 0); \
        acc##g = __builtin_amdgcn_mfma_f32_16x16x32_f16(af_##g##_3, bf3, acc##g, 0, 0, 0); \
        acc##g = __builtin_amdgcn_mfma_f32_16x16x32_f16(af_##g##_4, bf4, acc##g, 0, 0, 0);
        MFMA_TILE(0) MFMA_TILE(1) MFMA_TILE(2) MFMA_TILE(3)
#undef MFMA_TILE

        // ---- Phase B in-register: rows base..base+3 (m==0 lanes) ----
        if (m == 0) {
            half4_t hv4;
            #pragma unroll
            for (int r = 0; r < 4; ++r) {
                float gi = sigm(acc0[r]);        // col 0, row base+r
                float gf = sigm(acc1[r]);
                float gg = tanh_fast(acc2[r]);
                float go = sigm(acc3[r]);
                c[r] = fmaf(gf, c[r], gi * gg);
                hv4[r] = (_Float16)(go * tanh_fast(c[r]));
            }
            *(half4_t*)&hbuf[1 - p][base] = hv4;                  // next h
            *(half4_t*)(h_hist + (size_t)t * HDIM + base) = hv4;  // floats past barrier
        }
        xcur = xnext;
        block_sync_lds();   // ONE barrier: h_t writes visible for t+1 reads
    }
}

// ================= Kernel 2: out[t] = tanh(h_t).W_out + b =================
__global__ __launch_bounds__(256)
void out_proj(const _Float16* __restrict__ h_hist,
              const float* __restrict__ W_out,
              const float* __restrict__ b_out,
              float* __restrict__ out)
{
    const int lane  = threadIdx.x & 63;
    const int gwave = (blockIdx.x * 256 + threadIdx.x) >> 6;
    const int nwave = (gridDim.x * 256) >> 6;

    const float wo0 = W_out[2 * lane + 0];
    const float wo1 = W_out[2 * lane + 1];
    const float bout = b_out[0];

    for (int t = gwave; t < S_LEN; t += nwave) {
        half2_t hv = ((const half2_t*)(h_hist + (size_t)t * HDIM))[lane];
        float p = tanh_fast((float)hv.x) * wo0 + tanh_fast((float)hv.y) * wo1;
        #pragma unroll
        for (int off = 32; off > 0; off >>= 1)
            p += __shfl_xor(p, off, 64);
        if (lane == 0) out[t] = p + bout;
    }
}

// ================= Fallback: fused single kernel (ws too small) ===========
#define H_HI_OFF 144
__global__ __launch_bounds__(1024)
__attribute__((amdgpu_waves_per_eu(4, 4)))
void lstm_seq_full(const float* __restrict__ x,
                   const float* __restrict__ h0,
                   const float* __restrict__ c0,
                   const float* __restrict__ W_ih,
                   const float* __restrict__ W_hh,
                   const float* __restrict__ b_ih,
                   const float* __restrict__ b_hh,
                   const float* __restrict__ W_out,
                   const float* __restrict__ b_out,
                   float* __restrict__ out)
{
    __shared__ __align__(16) unsigned char h_raw[2 * H_HI_OFF];
    __shared__ float gates_part[2 * 512];
    __shared__ float red_sh[2];

    const int tid  = threadIdx.x;
    const int j    = tid >> 1;
    const int half = tid & 1;

    const float2* wr2 = (const float2*)(W_hh + j * HDIM + half * 64);
#define WDEF(i) half2_t W##i; { float2 t = wr2[i]; \
        W##i.x = (_Float16)t.x; W##i.y = (_Float16)t.y; } \
        asm volatile("" : "+v"(W##i));
    WDEF(0)  WDEF(1)  WDEF(2)  WDEF(3)  WDEF(4)  WDEF(5)  WDEF(6)  WDEF(7)
    WDEF(8)  WDEF(9)  WDEF(10) WDEF(11) WDEF(12) WDEF(13) WDEF(14) WDEF(15)
    WDEF(16) WDEF(17) WDEF(18) WDEF(19) WDEF(20) WDEF(21) WDEF(22) WDEF(23)
    WDEF(24) WDEF(25) WDEF(26) WDEF(27) WDEF(28) WDEF(29) WDEF(30) WDEF(31)
#undef WDEF

    float wih0 = 0.0f, wih1 = 0.0f, bias = 0.0f;
    if (half == 0) {
        wih0 = W_ih[2 * j + 0];
        wih1 = W_ih[2 * j + 1];
        bias = b_ih[j] + b_hh[j];
    }

    float c = 0.0f, wout = 0.0f;
    _Float16* hw = (_Float16*)(h_raw + ((tid < 64) ? 2 * tid
                                                   : H_HI_OFF + 2 * (tid - 64)));
    if (tid < HDIM) {
        c = c0[tid];
        wout = W_out[tid];
        *hw = (_Float16)h0[tid];
    }
    const float bout = b_out[0];
    __syncthreads();

    const float2* xp = (const float2*)x;
    float2 xcur = xp[0];
    const half8_t* hp = (const half8_t*)(h_raw + half * H_HI_OFF);

    #pragma unroll 1
    for (int t = 0; t < S_LEN; ++t) {
        const int tn = (t + 1 < S_LEN) ? (t + 1) : (S_LEN - 1);
        float2 xnext = xp[tn];

        float a0 = fmaf(wih0, xcur.x, fmaf(wih1, xcur.y, bias));
        float a1 = 0.0f, a2 = 0.0f, a3 = 0.0f;

#define CHUNK(cc, w0_, w1_, w2_, w3_) {                         \
        half8_t hv = hp[cc];                                    \
        half2_t p0 = { hv[0], hv[1] };                          \
        half2_t p1 = { hv[2], hv[3] };                          \
        half2_t p2 = { hv[4], hv[5] };                          \
        half2_t p3 = { hv[6], hv[7] };                          \
        a0 = dot2(w0_, p0, a0);                                 \
        a1 = dot2(w1_, p1, a1);                                 \
        a2 = dot2(w2_, p2, a2);                                 \
        a3 = dot2(w3_, p3, a3); }
        CHUNK(0, W0,  W1,  W2,  W3)
        CHUNK(1, W4,  W5,  W6,  W7)
        CHUNK(2, W8,  W9,  W10, W11)
        CHUNK(3, W12, W13, W14, W15)
        CHUNK(4, W16, W17, W18, W19)
        CHUNK(5, W20, W21, W22, W23)
        CHUNK(6, W24, W25, W26, W27)
        CHUNK(7, W28, W29, W30, W31)
#undef CHUNK

        gates_part[half * 512 + j] = (a0 + a1) + (a2 + a3);
        __syncthreads();

        if (tid < HDIM) {
            float gi = sigm(gates_part[tid]            + gates_part[tid + 512]);
            float gf = sigm(gates_part[tid + 128]      + gates_part[tid + 640]);
            float gg = tanh_fast(gates_part[tid + 256] + gates_part[tid + 768]);
            float go = sigm(gates_part[tid + 384]      + gates_part[tid + 896]);
            c = fmaf(gf, c, gi * gg);
            float h = go * tanh_fast(c);
            *hw = (_Float16)h;

            float p = tanh_fast(h) * wout;
            #pragma unroll
            for (int off = 32; off > 0; off >>= 1)
                p += __shfl_xor(p, off, 64);
            if ((tid & 63) == 0) red_sh[tid >> 6] = p;
        }
        __syncthreads();

        if (tid == 0) out[t] = red_sh[0] + red_sh[1] + bout;
        xcur = xnext;
    }
}

extern "C" void kernel_launch(void* const* d_in, const int* in_sizes, int n_in,
                              void* d_out, int out_size, void* d_ws, size_t ws_size,
                              hipStream_t stream) {
    const float* x     = (const float*)d_in[0];
    const float* h0    = (const float*)d_in[1];
    const float* c0    = (const float*)d_in[2];
    const float* W_ih  = (const float*)d_in[3];
    const float* W_hh  = (const float*)d_in[4];
    const float* b_ih  = (const float*)d_in[5];
    const float* b_hh  = (const float*)d_in[6];
    const float* W_out = (const float*)d_in[7];
    const float* b_out = (const float*)d_in[8];

    const size_t need = (size_t)S_LEN * HDIM * sizeof(_Float16);  // 16 MiB
    if (ws_size >= need) {
        _Float16* h_hist = (_Float16*)d_ws;
        lstm_seq_mfma<<<dim3(1), dim3(512), 0, stream>>>(
            x, h0, c0, W_ih, W_hh, b_ih, b_hh, h_hist);
        out_proj<<<dim3(1024), dim3(256), 0, stream>>>(
            h_hist, W_out, b_out, (float*)d_out);
    } else {
        lstm_seq_full<<<dim3(1), dim3(1024), 0, stream>>>(
            x, h0, c0, W_ih, W_hh, b_ih, b_hh, W_out, b_out, (float*)d_out);
    }
}